// Round 20
// baseline (48.594 us; speedup 1.0000x reference)
//
#include <hip/hip_runtime.h>
#include <math.h>

#define LOG2E  1.4426950408889634f
#define LN2    0.6931471805599453f

// Problem constants (fixed by setup_inputs)
#define T_DIM 1024
#define B_DIM 128
#define C_DIM 256
#define S_DIM 64
#define CH 16                   // timesteps per chunk
#define NCHD 32                 // chunks per direction (511 steps + 1 pad)
#define RBN 4                   // raw-row ring (64 KB)
#define PBN 6                   // converted-pair ring (48 KB)

__device__ __forceinline__ float fexp2(float x) { return __builtin_amdgcn_exp2f(x); }
__device__ __forceinline__ float flog2(float x) { return __builtin_amdgcn_logf(x); }

// lane i <- lane i-1 (shr) / lane i+1 (shl); vacated lanes <- 0.
__device__ __forceinline__ int dpp_shr1_i(int x) {
    return __builtin_amdgcn_update_dpp(0, x, 0x138, 0xF, 0xF, false);
}
__device__ __forceinline__ int dpp_shl1_i(int x) {
    return __builtin_amdgcn_update_dpp(0, x, 0x130, 0xF, 0xF, false);
}

#define GLOAD_LDS16(gp, lp)                                                    \
    __builtin_amdgcn_global_load_lds(                                          \
        (const __attribute__((address_space(1))) void*)(gp),                   \
        (__attribute__((address_space(3))) void*)(lp), 16, 0, 0)

#define VMWAIT(N_) asm volatile("s_waitcnt vmcnt(" #N_ ")" ::: "memory")
#define LGKM0()    asm volatile("s_waitcnt lgkmcnt(0)" ::: "memory")
#define FENCE()                                                                \
    do { __builtin_amdgcn_sched_barrier(0);                                    \
         asm volatile("" ::: "memory"); } while (0)

// ONE DIRECTION PER BLOCK (grid = 256: blockIdx&1 = dir, >>1 = batch).
// Per block, the proven R18 4-wave pipeline: w1 stager (global_load_lds raw
// rows, owns vmcnt), w2/w3 converters (e1-gather + exp2 -> packed float2),
// w0 consumer (poll -> ds_read_b64 gather-ahead dbuf -> exp-free recursion).
// fwd: alpha over t=1..511 -> ws[b][0..128] = log2 alpha_511.
// bwd: beta over t=1022..512 -> ws[128+b][0..128] = log2 gamma (from b_512).
__global__ __launch_bounds__(256) void ctc_scan_kernel(
    const float* __restrict__ log_probs,    // (T, B, C)
    const int* __restrict__ targets,        // (B, S)
    const int* __restrict__ target_lengths, // (B,)
    float* __restrict__ ws)                 // 256*129 floats
{
    const int bx = blockIdx.x;
    const int b = bx >> 1;
    const int dir = bx & 1;    // 0 = forward, 1 = backward
    const int tid = threadIdx.x;
    const int lane = tid & 63;
    const int wid = tid >> 6;  // 0 consumer, 1 stager, 2 conv-even, 3 conv-odd

    __shared__ float  rbuf[RBN][CH][C_DIM];  // 64 KB raw class rows
    __shared__ float2 pcv[PBN][CH][64];      // 48 KB converted {plv,pbv}
    __shared__ int sf, cvE, cvO, cf;

    const int e1 = targets[b * S_DIM + lane];
    const int ep = (lane > 0) ? targets[b * S_DIM + lane - 1] : 0;
    const bool skipf = (lane > 0) && (e1 != ep);   // fwd: s-2 -> s
    const int en = dpp_shl1_i(e1);                 // next lane's label
    const bool skipb = (lane < 63) && (en != e1);  // bwd: s -> s+2
    const bool is63 = (lane == 63);
    const int len = target_lengths[b];

    const float* base = log_probs + (size_t)b * C_DIM;
    const size_t stride = (size_t)B_DIM * C_DIM;

    if (tid == 0) { sf = 0; cvE = 0; cvO = 0; cf = 0; }
    __syncthreads();

    volatile int* vsf = &sf; volatile int* vcE = &cvE;
    volatile int* vcO = &cvO; volatile int* vcf = &cf;

    // Slot (c,k) timestep: fwd 1+16c+k, bwd 1022-16c-k (all in [1,1023]).
    const int t0d = dir ? 1022 : 1;
    const int sgn = dir ? -1 : 1;

#define POLLG(C_)                                                              \
    do { const int cc_ = (C_);                                                 \
         if (cc_ & 1) { while (*vcO < (cc_ + 1) / 2) { } }                     \
         else         { while (*vcE < cc_ / 2 + 1) { } }                       \
         FENCE(); } while (0)

#define GATHER_G(PLX, PBX, SLOT)                                               \
    do { _Pragma("unroll")                                                     \
         for (int k_ = 0; k_ < CH; ++k_) {                                     \
             float2 v_ = pcv[SLOT][k_][lane];                                  \
             PLX[k_] = v_.x; PBX[k_] = v_.y;                                   \
         } } while (0)

    if (wid == 1) {
        // STAGER
        for (int c = 0; c < NCHD; ++c) {
            if (c >= RBN) {
                const int d_ = c - RBN;  // chunk previously in this rbuf slot
                if (d_ & 1) { while (*vcO < (d_ + 1) / 2) __builtin_amdgcn_s_sleep(1); }
                else        { while (*vcE < d_ / 2 + 1) __builtin_amdgcn_s_sleep(1); }
                FENCE();
            }
            const int rb_ = c & (RBN - 1);
            #pragma unroll
            for (int k_ = 0; k_ < CH; ++k_) {
                const int t_ = t0d + sgn * (16 * c + k_);
                GLOAD_LDS16(base + (size_t)t_ * stride + 4 * lane,
                            &rbuf[rb_][k_][0]);
            }
            VMWAIT(32);
            FENCE();
            if (c >= 2 && lane == 0) *vsf = c - 1;
        }
        VMWAIT(16); FENCE(); if (lane == 0) *vsf = NCHD - 1;
        VMWAIT(0);  FENCE(); if (lane == 0) *vsf = NCHD;
    } else if (wid >= 2) {
        // CONVERTER (par 0 = even chunks, par 1 = odd chunks)
        const int par = wid - 2;
        for (int c = par; c < NCHD; c += 2) {
            while (*vsf < c + 1) { }
            if (c >= PBN) {
                while (*vcf < c - PBN + 1) __builtin_amdgcn_s_sleep(1);
            }
            FENCE();
            const int rb_ = c & (RBN - 1);
            const int pb_ = c % PBN;
            #pragma unroll
            for (int k_ = 0; k_ < CH; ++k_) {
                float pl_ = rbuf[rb_][k_][e1];
                float pbl_ = rbuf[rb_][k_][0];
                float2 v_;
                v_.x = fexp2(pl_ * LOG2E);
                v_.y = fexp2(pbl_ * LOG2E);
                pcv[pb_][k_][lane] = v_;
            }
            LGKM0();
            if (lane == 0) { if (par) *vcO = (c + 1) / 2; else *vcE = c / 2 + 1; }
        }
    } else if (dir == 0) {
        // ===== FORWARD alpha consumer: t = 1..511 =====
        float a0, a1, a2; int el = 0, dexp = 0;
        {
            float i0 = base[0], ie = base[e1];
            a0 = (lane == 0) ? fexp2(i0 * LOG2E) : 0.0f;
            a1 = (lane == 0) ? fexp2(ie * LOG2E) : 0.0f;
            a2 = 0.0f;
        }
#define RESCALE_F()                                                            \
    do { float mx_ = fmaxf(a0, fmaxf(a1, a2));                                 \
         int eb_ = (int)((__float_as_uint(mx_) >> 23) & 0xFFu) - 127;          \
         el += eb_;                                                            \
         float sc_ = __uint_as_float((unsigned)(127 - eb_) << 23);             \
         a0 *= sc_; a1 *= sc_; a2 *= sc_; } while (0)
#define ACT_STEP_F(PBV, PLV, K_)                                               \
    do { float am1_ = __int_as_float(dpp_shr1_i(__float_as_int(a1)));          \
         int eprev_ = dpp_shr1_i(el);                                          \
         int iz_ = __float_as_int(a0) | __float_as_int(a1) |                   \
                   __float_as_int(a2);                                         \
         int ele_ = (iz_ == 0) ? eprev_ : el;                                  \
         float am1s_ = ldexpf(am1_, eprev_ - ele_);                            \
         el = ele_;                                                            \
         float n0_ = (a0 + am1s_) * (PBV);                                     \
         float s2_ = skipf ? am1s_ : 0.0f;                                     \
         float n1_ = (a1 + a0 + s2_) * (PLV);                                  \
         float n2_ = (a2 + a1) * (PBV);                                        \
         a0 = n0_; a1 = n1_; a2 = n2_;                                         \
         if (((K_) & 3) == 3) RESCALE_F(); } while (0)
#define STREAM_STEP_F(PBV, PLV)                                                \
    do { float am1_ = __int_as_float(dpp_shr1_i(__float_as_int(a1)));          \
         float am1s_ = ldexpf(am1_, dexp);                                     \
         float n0_ = (a0 + am1s_) * (PBV);                                     \
         float s2_ = skipf ? am1s_ : 0.0f;                                     \
         float n1_ = (a1 + a0 + s2_) * (PLV);                                  \
         float n2_ = (a2 + a1) * (PBV);                                        \
         a0 = n0_; a1 = n1_; a2 = n2_; } while (0)
#define ACT_FROM_F(PLX, PBX)                                                   \
    do { _Pragma("unroll")                                                     \
         for (int k_ = 0; k_ < CH; ++k_) ACT_STEP_F(PBX[k_], PLX[k_], k_);     \
    } while (0)
#define STREAM_FROM_F(PLX, PBX)                                                \
    do { _Pragma("unroll")                                                     \
         for (int q_ = 0; q_ < 4; ++q_) {                                      \
             dexp = dpp_shr1_i(el) - el;                                       \
             STREAM_STEP_F(PBX[4 * q_ + 0], PLX[4 * q_ + 0]);                  \
             STREAM_STEP_F(PBX[4 * q_ + 1], PLX[4 * q_ + 1]);                  \
             STREAM_STEP_F(PBX[4 * q_ + 2], PLX[4 * q_ + 2]);                  \
             STREAM_STEP_F(PBX[4 * q_ + 3], PLX[4 * q_ + 3]);                  \
             RESCALE_F(); } } while (0)
#define TAIL_FROM_F(PLX, PBX)                                                  \
    do { _Pragma("unroll")                                                     \
         for (int q_ = 0; q_ < 3; ++q_) {                                      \
             dexp = dpp_shr1_i(el) - el;                                       \
             STREAM_STEP_F(PBX[4 * q_ + 0], PLX[4 * q_ + 0]);                  \
             STREAM_STEP_F(PBX[4 * q_ + 1], PLX[4 * q_ + 1]);                  \
             STREAM_STEP_F(PBX[4 * q_ + 2], PLX[4 * q_ + 2]);                  \
             STREAM_STEP_F(PBX[4 * q_ + 3], PLX[4 * q_ + 3]);                  \
             RESCALE_F(); }                                                    \
         dexp = dpp_shr1_i(el) - el;                                           \
         STREAM_STEP_F(PBX[12], PLX[12]);                                      \
         STREAM_STEP_F(PBX[13], PLX[13]);                                      \
         STREAM_STEP_F(PBX[14], PLX[14]); } while (0)

        float plA[CH], pbA[CH], plB[CH], pbB[CH];
        POLLG(0);
        GATHER_G(plA, pbA, 0);
        for (int c = 0; c < 10; c += 2) {
            POLLG(c + 1); GATHER_G(plB, pbB, (c + 1) % PBN);
            ACT_FROM_F(plA, pbA); if (lane == 0) *vcf = c + 1;
            POLLG(c + 2); GATHER_G(plA, pbA, (c + 2) % PBN);
            ACT_FROM_F(plB, pbB); if (lane == 0) *vcf = c + 2;
        }
        for (int c = 10; c < 30; c += 2) {
            POLLG(c + 1); GATHER_G(plB, pbB, (c + 1) % PBN);
            STREAM_FROM_F(plA, pbA); if (lane == 0) *vcf = c + 1;
            POLLG(c + 2); GATHER_G(plA, pbA, (c + 2) % PBN);
            STREAM_FROM_F(plB, pbB); if (lane == 0) *vcf = c + 2;
        }
        POLLG(NCHD - 1);
        GATHER_G(plB, pbB, (NCHD - 1) % PBN);
        STREAM_FROM_F(plA, pbA);                 // chunk 30
        if (lane == 0) *vcf = NCHD - 1;
        TAIL_FROM_F(plB, pbB);                   // chunk 31 (15 steps)
        if (lane == 0) *vcf = NCHD;

        float* oF = ws + (size_t)b * 129;
        oF[lane] = flog2(a0) + (float)el;
        oF[64 + lane] = flog2(a1) + (float)el;
        if (is63) oF[128] = flog2(a2) + (float)el;
    } else {
        // ===== BACKWARD beta consumer: t = 1022..512 =====
        float b0, b1, b2; int elB = 0, dexB = 0, dex0 = 0;
        {
            const float* rowT = base + (size_t)(T_DIM - 1) * stride;
            float lpb_ = rowT[0], lpl_ = rowT[e1];
            b1 = (lane == len - 1) ? fexp2(lpl_ * LOG2E) : 0.0f;
            b0 = (lane == len && len < S_DIM) ? fexp2(lpb_ * LOG2E) : 0.0f;
            b2 = (len == S_DIM && is63) ? fexp2(lpb_ * LOG2E) : 0.0f;
        }
#define RESCALE_B()                                                            \
    do { float mx_ = fmaxf(b0, fmaxf(b1, b2));                                 \
         int eb_ = (int)((__float_as_uint(mx_) >> 23) & 0xFFu) - 127;          \
         elB += eb_;                                                           \
         float sc_ = __uint_as_float((unsigned)(127 - eb_) << 23);             \
         b0 *= sc_; b1 *= sc_; b2 *= sc_; } while (0)
#define ACT_STEP_B(PBV, PLV, K_)                                               \
    do { float nb0_ = __int_as_float(dpp_shl1_i(__float_as_int(b0)));          \
         nb0_ = is63 ? b2 : nb0_;                                              \
         float nb1_ = __int_as_float(dpp_shl1_i(__float_as_int(b1)));          \
         int en_ = dpp_shl1_i(elB);                                            \
         int iz_ = __float_as_int(b0) | __float_as_int(b1) |                   \
                   __float_as_int(b2);                                         \
         int eln_ = (iz_ == 0) ? en_ : elB;                                    \
         int d0_ = is63 ? (elB - eln_) : (en_ - eln_);                         \
         float nb0a_ = ldexpf(nb0_, d0_);                                      \
         float nb1a_ = ldexpf(nb1_, en_ - eln_);                               \
         elB = eln_;                                                           \
         float n0_ = (b0 + b1) * (PBV);                                        \
         float n1_ = (b1 + nb0a_ + (skipb ? nb1a_ : 0.0f)) * (PLV);            \
         float n2_ = b2 * (PBV);                                               \
         b0 = n0_; b1 = n1_; b2 = n2_;                                         \
         if (((K_) & 3) == 3) RESCALE_B(); } while (0)
#define STREAM_STEP_B(PBV, PLV)                                                \
    do { float nb0_ = __int_as_float(dpp_shl1_i(__float_as_int(b0)));          \
         nb0_ = is63 ? b2 : nb0_;                                              \
         float nb1_ = __int_as_float(dpp_shl1_i(__float_as_int(b1)));          \
         float nb0a_ = ldexpf(nb0_, dex0);                                     \
         float nb1a_ = ldexpf(nb1_, dexB);                                     \
         float n0_ = (b0 + b1) * (PBV);                                        \
         float n1_ = (b1 + nb0a_ + (skipb ? nb1a_ : 0.0f)) * (PLV);            \
         float n2_ = b2 * (PBV);                                               \
         b0 = n0_; b1 = n1_; b2 = n2_; } while (0)
#define SET_DEX_B()                                                            \
    do { dexB = dpp_shl1_i(elB) - elB; dex0 = is63 ? 0 : dexB; } while (0)
#define ACT_FROM_B(PLX, PBX)                                                   \
    do { _Pragma("unroll")                                                     \
         for (int k_ = 0; k_ < CH; ++k_) ACT_STEP_B(PBX[k_], PLX[k_], k_);     \
    } while (0)
#define STREAM_FROM_B(PLX, PBX)                                                \
    do { _Pragma("unroll")                                                     \
         for (int q_ = 0; q_ < 4; ++q_) {                                      \
             SET_DEX_B();                                                      \
             STREAM_STEP_B(PBX[4 * q_ + 0], PLX[4 * q_ + 0]);                  \
             STREAM_STEP_B(PBX[4 * q_ + 1], PLX[4 * q_ + 1]);                  \
             STREAM_STEP_B(PBX[4 * q_ + 2], PLX[4 * q_ + 2]);                  \
             STREAM_STEP_B(PBX[4 * q_ + 3], PLX[4 * q_ + 3]);                  \
             RESCALE_B(); } } while (0)
#define TAIL_FROM_B(PLX, PBX)                                                  \
    do { _Pragma("unroll")                                                     \
         for (int q_ = 0; q_ < 3; ++q_) {                                      \
             SET_DEX_B();                                                      \
             STREAM_STEP_B(PBX[4 * q_ + 0], PLX[4 * q_ + 0]);                  \
             STREAM_STEP_B(PBX[4 * q_ + 1], PLX[4 * q_ + 1]);                  \
             STREAM_STEP_B(PBX[4 * q_ + 2], PLX[4 * q_ + 2]);                  \
             STREAM_STEP_B(PBX[4 * q_ + 3], PLX[4 * q_ + 3]);                  \
             RESCALE_B(); }                                                    \
         SET_DEX_B();                                                          \
         STREAM_STEP_B(PBX[12], PLX[12]);                                      \
         STREAM_STEP_B(PBX[13], PLX[13]);                                      \
         STREAM_STEP_B(PBX[14], PLX[14]); } while (0)

        float plA[CH], pbA[CH], plB[CH], pbB[CH];
        POLLG(0);
        GATHER_G(plA, pbA, 0);
        for (int c = 0; c < 10; c += 2) {
            POLLG(c + 1); GATHER_G(plB, pbB, (c + 1) % PBN);
            ACT_FROM_B(plA, pbA); if (lane == 0) *vcf = c + 1;
            POLLG(c + 2); GATHER_G(plA, pbA, (c + 2) % PBN);
            ACT_FROM_B(plB, pbB); if (lane == 0) *vcf = c + 2;
        }
        for (int c = 10; c < 30; c += 2) {
            POLLG(c + 1); GATHER_G(plB, pbB, (c + 1) % PBN);
            STREAM_FROM_B(plA, pbA); if (lane == 0) *vcf = c + 1;
            POLLG(c + 2); GATHER_G(plA, pbA, (c + 2) % PBN);
            STREAM_FROM_B(plB, pbB); if (lane == 0) *vcf = c + 2;
        }
        POLLG(NCHD - 1);
        GATHER_G(plB, pbB, (NCHD - 1) % PBN);
        STREAM_FROM_B(plA, pbA);                 // chunk 30
        if (lane == 0) *vcf = NCHD - 1;
        TAIL_FROM_B(plB, pbB);                   // chunk 31 (15 steps)
        if (lane == 0) *vcf = NCHD;

        // gamma[s] from beta_512 (exponent-aligned), write log2 gamma.
        {
            float nb0_ = __int_as_float(dpp_shl1_i(__float_as_int(b0)));
            nb0_ = is63 ? b2 : nb0_;
            float nb1_ = __int_as_float(dpp_shl1_i(__float_as_int(b1)));
            int en_ = dpp_shl1_i(elB);
            int d_ = is63 ? 0 : (en_ - elB);
            float nb0a_ = ldexpf(nb0_, d_);
            float nb1a_ = ldexpf(nb1_, d_);
            float g0 = b0 + b1;
            float g1 = b1 + nb0a_ + (skipb ? nb1a_ : 0.0f);
            float* oB = ws + (size_t)(B_DIM * 129) + (size_t)b * 129;
            oB[lane] = flog2(g0) + (float)elB;
            oB[64 + lane] = flog2(g1) + (float)elB;
            if (is63) oB[128] = flog2(b2) + (float)elB;
        }
    }
}

// COMBINE + REDUCE: one block, 8 waves; wave w handles 16 batches.
// P_b = LSE_s( log2 alpha_511[s] + log2 gamma[s] ); loss = -P*ln2.
__global__ __launch_bounds__(512) void ctc_combine_kernel(
    const float* __restrict__ ws,
    const int* __restrict__ target_lengths,
    float* __restrict__ out)
{
    const int tid = threadIdx.x;
    const int lane = tid & 63;
    const int w = tid >> 6;  // 0..7
    __shared__ float part[8];

    float acc = 0.0f;
    for (int i = 0; i < 16; ++i) {
        const int b = w * 16 + i;
        const float* F = ws + (size_t)b * 129;
        const float* G = ws + (size_t)(B_DIM * 129) + (size_t)b * 129;
        float q0 = F[lane] + G[lane];
        float q1 = F[64 + lane] + G[64 + lane];
        float q2 = (lane == 63) ? (F[128] + G[128]) : -1e30f;
        float m = fmaxf(q0, fmaxf(q1, q2));
        #pragma unroll
        for (int off = 1; off < 64; off <<= 1) {
            m = fmaxf(m, __shfl_xor(m, off, 64));
        }
        float s = fexp2(q0 - m) + fexp2(q1 - m) + fexp2(q2 - m);
        #pragma unroll
        for (int off = 1; off < 64; off <<= 1) {
            s += __shfl_xor(s, off, 64);
        }
        float lse2 = m + flog2(s);
        float loss = -(lse2 * LN2);
        if (!isfinite(loss) || !(loss < 1e29f)) loss = 0.0f;
        acc += loss / (float)target_lengths[b];
    }
    if (lane == 0) part[w] = acc;
    __syncthreads();
    if (tid == 0) {
        float t = 0.0f;
        #pragma unroll
        for (int i = 0; i < 8; ++i) t += part[i];
        out[0] = t / (float)B_DIM;
    }
}

extern "C" void kernel_launch(void* const* d_in, const int* in_sizes, int n_in,
                              void* d_out, int out_size, void* d_ws, size_t ws_size,
                              hipStream_t stream) {
    const float* log_probs = (const float*)d_in[0];
    const int* targets = (const int*)d_in[1];
    const int* target_lengths = (const int*)d_in[2];
    float* out = (float*)d_out;
    float* ws = (float*)d_ws;  // 256*129 floats

    ctc_scan_kernel<<<2 * B_DIM, 256, 0, stream>>>(log_probs, targets,
                                                   target_lengths, ws);
    ctc_combine_kernel<<<1, 512, 0, stream>>>(ws, target_lengths, out);
}

// Round 21
// 44.679 us; speedup vs baseline: 1.0876x; 1.0876x over previous
//
#include <hip/hip_runtime.h>
#include <math.h>

#define LOG2E  1.4426950408889634f
#define LN2    0.6931471805599453f

// Problem constants (fixed by setup_inputs)
#define T_DIM 1024
#define B_DIM 128
#define C_DIM 256
#define S_DIM 64
#define CH 32                  // timesteps per chunk (halved handoff count)
#define NCH (T_DIM / CH)       // 32 chunks
#define RBN 3                  // raw-row ring (96 KB)
#define PBN 3                  // converted-pair ring (48 KB)

__device__ __forceinline__ float fexp2(float x) { return __builtin_amdgcn_exp2f(x); }
__device__ __forceinline__ float flog2(float x) { return __builtin_amdgcn_logf(x); }

// lane i <- lane i-1; lane 0 <- 0. wave_shr:1 DPP (gfx9 ctrl 0x138).
__device__ __forceinline__ int dpp_shr1_i(int x) {
    return __builtin_amdgcn_update_dpp(0, x, 0x138, 0xF, 0xF, false);
}

#define GLOAD_LDS16(gp, lp)                                                    \
    __builtin_amdgcn_global_load_lds(                                          \
        (const __attribute__((address_space(1))) void*)(gp),                   \
        (__attribute__((address_space(3))) void*)(lp), 16, 0, 0)

#define VMWAIT(N_) asm volatile("s_waitcnt vmcnt(" #N_ ")" ::: "memory")
#define LGKM0()    asm volatile("s_waitcnt lgkmcnt(0)" ::: "memory")
#define FENCE()                                                                \
    do { __builtin_amdgcn_sched_barrier(0);                                    \
         asm volatile("" ::: "memory"); } while (0)

// R18 4-WAVE PIPELINE, CH=32 (one block per batch element):
//   w1 STAGER:     global_load_lds raw class rows -> rbuf ring, owns vmcnt,
//                  publishes sf = # chunks landed.
//   w2/w3 CONVERT: alternating chunks: e1-gather + exp2 -> packed float2.
//   w0 CONSUMER:   poll -> 64 ds_read_b64 (gather-ahead register dbuf) ->
//                  32 exp-free recursion steps.
// Alpha: LINEAR domain, per-lane exponent el (true_alpha = a * 2^el).
__global__ __launch_bounds__(256) void ctc_alpha_kernel(
    const float* __restrict__ log_probs,    // (T, B, C)
    const int* __restrict__ targets,        // (B, S)
    const int* __restrict__ target_lengths, // (B,)
    float* __restrict__ per_batch)          // (B,) loss_b / len_b
{
    const int b = blockIdx.x;
    const int tid = threadIdx.x;
    const int lane = tid & 63;
    const int wid = tid >> 6;  // 0 consumer, 1 stager, 2 conv-even, 3 conv-odd

    __shared__ float  rbuf[RBN][CH][C_DIM];  // 96 KB raw class rows
    __shared__ float2 pcv[PBN][CH][64];      // 48 KB converted {plv,pbv}
    __shared__ int sf, cvE, cvO, cf;

    const int e1 = targets[b * S_DIM + lane];
    const int ep = (lane > 0) ? targets[b * S_DIM + lane - 1] : 0;
    const bool skip = (lane > 0) && (e1 != ep);
    const bool is63 = (lane == 63);

    const float* base = log_probs + (size_t)b * C_DIM;
    const size_t stride = (size_t)B_DIM * C_DIM;

    // t = 0 init (linear domain, scale el=0) — consumer state.
    float i0 = base[0];
    float ie = base[e1];
    float a0 = (lane == 0) ? fexp2(i0 * LOG2E) : 0.0f;
    float a1 = (lane == 0) ? fexp2(ie * LOG2E) : 0.0f;
    float a2 = 0.0f;
    int el = 0;
    int dexp = 0;

    if (tid == 0) { sf = 0; cvE = 0; cvO = 0; cf = 0; }
    __syncthreads();  // the only barrier in the kernel

    volatile int* vsf = &sf; volatile int* vcE = &cvE;
    volatile int* vcO = &cvO; volatile int* vcf = &cf;

#define RESCALE()                                                              \
    do { float mx_ = fmaxf(a0, fmaxf(a1, a2));                                 \
         int eb_ = (int)((__float_as_uint(mx_) >> 23) & 0xFFu) - 127;          \
         el += eb_;                                                            \
         float sc_ = __uint_as_float((unsigned)(127 - eb_) << 23);             \
         a0 *= sc_; a1 *= sc_; a2 *= sc_; } while (0)

#define ACT_STEP(PBV, PLV, K_)                                                 \
    do { float am1_ = __int_as_float(dpp_shr1_i(__float_as_int(a1)));          \
         int eprev_ = dpp_shr1_i(el);                                          \
         int iz_ = __float_as_int(a0) | __float_as_int(a1) |                   \
                   __float_as_int(a2);                                         \
         int ele_ = (iz_ == 0) ? eprev_ : el;                                  \
         float am1s_ = ldexpf(am1_, eprev_ - ele_);                            \
         el = ele_;                                                            \
         float n0_ = (a0 + am1s_) * (PBV);                                     \
         float s2_ = skip ? am1s_ : 0.0f;                                      \
         float n1_ = (a1 + a0 + s2_) * (PLV);                                  \
         float n2_ = (a2 + a1) * (PBV);                                        \
         a0 = n0_; a1 = n1_; a2 = n2_;                                         \
         if (((K_) & 3) == 3) RESCALE(); } while (0)

#define STREAM_STEP(PBV, PLV)                                                  \
    do { float am1_ = __int_as_float(dpp_shr1_i(__float_as_int(a1)));          \
         float am1s_ = ldexpf(am1_, dexp);                                     \
         float n0_ = (a0 + am1s_) * (PBV);                                     \
         float s2_ = skip ? am1s_ : 0.0f;                                      \
         float n1_ = (a1 + a0 + s2_) * (PLV);                                  \
         float n2_ = (a2 + a1) * (PBV);                                        \
         a0 = n0_; a1 = n1_; a2 = n2_; } while (0)

#define POLLG(C_)                                                              \
    do { const int cc_ = (C_);                                                 \
         if (cc_ & 1) { while (*vcO < (cc_ + 1) / 2) { } }                     \
         else         { while (*vcE < cc_ / 2 + 1) { } }                       \
         FENCE(); } while (0)

#define GATHER_G(PLX, PBX, SLOT)                                               \
    do { _Pragma("unroll")                                                     \
         for (int k_ = 0; k_ < CH; ++k_) {                                     \
             float2 v_ = pcv[SLOT][k_][lane];                                  \
             PLX[k_] = v_.x; PBX[k_] = v_.y;                                   \
         } } while (0)

#define ACT_FROM(PLX, PBX)                                                     \
    do { _Pragma("unroll")                                                     \
         for (int k_ = 0; k_ < CH; ++k_) ACT_STEP(PBX[k_], PLX[k_], k_);       \
    } while (0)

#define STREAM_FROM(PLX, PBX)                                                  \
    do { _Pragma("unroll")                                                     \
         for (int q_ = 0; q_ < 8; ++q_) {                                      \
             dexp = dpp_shr1_i(el) - el;                                       \
             STREAM_STEP(PBX[4 * q_ + 0], PLX[4 * q_ + 0]);                    \
             STREAM_STEP(PBX[4 * q_ + 1], PLX[4 * q_ + 1]);                    \
             STREAM_STEP(PBX[4 * q_ + 2], PLX[4 * q_ + 2]);                    \
             STREAM_STEP(PBX[4 * q_ + 3], PLX[4 * q_ + 3]);                    \
             RESCALE(); } } while (0)

#define TAIL_FROM(PLX, PBX)                                                    \
    do { _Pragma("unroll")                                                     \
         for (int q_ = 0; q_ < 7; ++q_) {                                      \
             dexp = dpp_shr1_i(el) - el;                                       \
             STREAM_STEP(PBX[4 * q_ + 0], PLX[4 * q_ + 0]);                    \
             STREAM_STEP(PBX[4 * q_ + 1], PLX[4 * q_ + 1]);                    \
             STREAM_STEP(PBX[4 * q_ + 2], PLX[4 * q_ + 2]);                    \
             STREAM_STEP(PBX[4 * q_ + 3], PLX[4 * q_ + 3]);                    \
             RESCALE(); }                                                      \
         dexp = dpp_shr1_i(el) - el;                                           \
         STREAM_STEP(PBX[28], PLX[28]);                                        \
         STREAM_STEP(PBX[29], PLX[29]);                                        \
         STREAM_STEP(PBX[30], PLX[30]); } while (0)

    if (wid == 1) {
        // STAGER: chunk c covers t = 1+32c .. 32+32c (chunk 31: t<=1023 pad).
        for (int c = 0; c < NCH; ++c) {
            if (c >= RBN) {
                const int d_ = c - RBN;  // previous occupant: must be converted
                if (d_ & 1) { while (*vcO < (d_ + 1) / 2) __builtin_amdgcn_s_sleep(1); }
                else        { while (*vcE < d_ / 2 + 1) __builtin_amdgcn_s_sleep(1); }
                FENCE();
            }
            const int rb_ = c % RBN;
            #pragma unroll
            for (int k_ = 0; k_ < CH; ++k_) {
                int t_ = 1 + CH * c + k_;
                t_ = (t_ < T_DIM) ? t_ : (T_DIM - 1);
                GLOAD_LDS16(base + (size_t)t_ * stride + 4 * lane,
                            &rbuf[rb_][k_][0]);
            }
            VMWAIT(32);  // chunk c-1 fully landed (32 newest = chunk c)
            FENCE();
            if (c >= 1 && lane == 0) *vsf = c;
        }
        VMWAIT(0);
        FENCE();
        if (lane == 0) *vsf = NCH;
    } else if (wid >= 2) {
        // CONVERTER (par 0 = even chunks, par 1 = odd chunks).
        const int par = wid - 2;
        for (int c = par; c < NCH; c += 2) {
            while (*vsf < c + 1) { }
            if (c >= PBN) {
                while (*vcf < c - PBN + 1) __builtin_amdgcn_s_sleep(1);
            }
            FENCE();
            const int rb_ = c % RBN;
            const int pb_ = c % PBN;
            #pragma unroll
            for (int k_ = 0; k_ < CH; ++k_) {
                float pl_ = rbuf[rb_][k_][e1];
                float pbl_ = rbuf[rb_][k_][0];
                float2 v_;
                v_.x = fexp2(pl_ * LOG2E);
                v_.y = fexp2(pbl_ * LOG2E);
                pcv[pb_][k_][lane] = v_;
            }
            LGKM0();
            if (lane == 0) { if (par) *vcO = (c + 1) / 2; else *vcE = c / 2 + 1; }
        }
    } else {
        // CONSUMER: gather-ahead register double-buffer, 32 chunks.
        float plA[CH], pbA[CH], plB[CH], pbB[CH];

        POLLG(0);
        GATHER_G(plA, pbA, 0);
        // ACT chunks 0..4 (t <= 160; activation completes ~t=130).
        POLLG(1); GATHER_G(plB, pbB, 1);
        ACT_FROM(plA, pbA);  if (lane == 0) *vcf = 1;   // chunk 0
        POLLG(2); GATHER_G(plA, pbA, 2);
        ACT_FROM(plB, pbB);  if (lane == 0) *vcf = 2;   // chunk 1
        POLLG(3); GATHER_G(plB, pbB, 0);
        ACT_FROM(plA, pbA);  if (lane == 0) *vcf = 3;   // chunk 2
        POLLG(4); GATHER_G(plA, pbA, 1);
        ACT_FROM(plB, pbB);  if (lane == 0) *vcf = 4;   // chunk 3
        POLLG(5); GATHER_G(plB, pbB, 2);
        ACT_FROM(plA, pbA);  if (lane == 0) *vcf = 5;   // chunk 4
        POLLG(6); GATHER_G(plA, pbA, 0);
        STREAM_FROM(plB, pbB); if (lane == 0) *vcf = 6; // chunk 5
        // Stream pairs: chunks (6,7), (8,9), ..., (28,29).
        for (int c = 6; c < 30; c += 2) {
            POLLG(c + 1); GATHER_G(plB, pbB, (c + 1) % PBN);
            STREAM_FROM(plA, pbA); if (lane == 0) *vcf = c + 1;  // chunk c
            POLLG(c + 2); GATHER_G(plA, pbA, (c + 2) % PBN);
            STREAM_FROM(plB, pbB); if (lane == 0) *vcf = c + 2;  // chunk c+1
        }
        // chunk 30 in A; gather 31, stream 30, tail 31 (31 steps).
        POLLG(31); GATHER_G(plB, pbB, 31 % PBN);
        STREAM_FROM(plA, pbA); if (lane == 0) *vcf = 31;
        TAIL_FROM(plB, pbB);   if (lane == 0) *vcf = NCH;

        // Terminal: states 2*len and 2*len-1 via uniform-index shuffles.
        const int len = target_lengths[b];
        float la0 = flog2(a0) + (float)el;
        float la1 = flog2(a1) + (float)el;
        float la2 = flog2(a2) + (float)el;
        float x = (len == S_DIM) ? __shfl(la2, 63, 64) : __shfl(la0, len, 64);
        float y = __shfl(la1, len - 1, 64);
        if (lane == 0) {
            float mx = fmaxf(x, y);
            float lse2 = mx + flog2(1.0f + fexp2(-fabsf(x - y)));
            float loss = -(lse2 * LN2);
            if (!isfinite(loss) || !(loss < 1e29f)) loss = 0.0f;
            per_batch[b] = loss / (float)len;
        }
    }

#undef TAIL_FROM
#undef STREAM_FROM
#undef ACT_FROM
#undef GATHER_G
#undef POLLG
#undef STREAM_STEP
#undef ACT_STEP
#undef RESCALE
}

// Single-wave deterministic reduction: mean over B of per_batch.
__global__ __launch_bounds__(64) void ctc_reduce_kernel(
    const float* __restrict__ per_batch, float* __restrict__ out)
{
    const int lane = threadIdx.x;
    float v = per_batch[lane] + per_batch[lane + 64];
    #pragma unroll
    for (int off = 32; off > 0; off >>= 1) {
        v += __shfl_down(v, off, 64);
    }
    if (lane == 0) out[0] = v / (float)B_DIM;
}

extern "C" void kernel_launch(void* const* d_in, const int* in_sizes, int n_in,
                              void* d_out, int out_size, void* d_ws, size_t ws_size,
                              hipStream_t stream) {
    const float* log_probs = (const float*)d_in[0];
    const int* targets = (const int*)d_in[1];
    const int* target_lengths = (const int*)d_in[2];
    float* out = (float*)d_out;
    float* per_batch = (float*)d_ws;  // B_DIM floats of scratch

    ctc_alpha_kernel<<<B_DIM, 256, 0, stream>>>(log_probs, targets,
                                                target_lengths, per_batch);
    ctc_reduce_kernel<<<1, 64, 0, stream>>>(per_batch, out);
}